// Round 2
// baseline (285.678 us; speedup 1.0000x reference)
//
#include <hip/hip_runtime.h>
#include <hip/hip_bf16.h>
#include <math.h>

// ---------------------------------------------------------------------------
// PSI_47931835024047: x@W_omega -> chunked phase cumsum/rotation -> LN ->
//                     W1+gelu -> W2 + residual.
// B=4 S=4096 D=512 C=64. All GEMMs bf16 MFMA.
// R11: GEMM2 256^2 ring kernel gains a 2-deep REGISTER fragment pipeline:
//      phase ks MFMAs slice ks from regs (read during phase ks-1) while
//      issuing ds_reads for slice ks+1 and stage(ks+4). The R10 failure
//      (MfmaUtil 26%, latency-bound: ds_read -> MFMA serial in-phase) is
//      removed -- each phase's critical path is pure MFMA. Counted vmcnt
//      (never 0 in steady state) + trailing lgkmcnt(0) drain before each
//      barrier keeps the slot-overwrite race-free. Frag sets are NAMED
//      (A/B) with a hand-unrolled 2-step loop body (no runtime indexing).
// ---------------------------------------------------------------------------

typedef __bf16 bf16x8 __attribute__((ext_vector_type(8)));
typedef __bf16 bf16x4 __attribute__((ext_vector_type(4)));
typedef __bf16 bf16x2 __attribute__((ext_vector_type(2)));
typedef float  f32x4  __attribute__((ext_vector_type(4)));

typedef __attribute__((address_space(1))) void* gas_ptr;
typedef __attribute__((address_space(3))) void* las_ptr;

// wave-uniform LDS base; each lane deposits 16 B at base + lane*16
__device__ __forceinline__ void load_lds16(const void* g, void* l) {
    __builtin_amdgcn_global_load_lds((gas_ptr)g, (las_ptr)l, 16, 0, 0);
}

// ---------------------------------------------------------------------------
// Fused prep: block ranges do (a) x->bf16 cast, (b) W_omega^T, (c) W1^T,
// (d) W2^T. One launch instead of four.
// ---------------------------------------------------------------------------
__device__ __forceinline__ void transpose_tile(const float* __restrict__ in,
                                               __bf16* __restrict__ out,
                                               int K, int N, int bx, int by,
                                               float (*tile)[33])
{
    const int tid = threadIdx.x;
    const int tx = tid & 31, ty = tid >> 5;       // (32, 8)
    const int n0 = bx * 32, k0 = by * 32;
    #pragma unroll
    for (int i = 0; i < 32; i += 8)
        tile[ty + i][tx] = in[(size_t)(k0 + ty + i) * N + n0 + tx];
    __syncthreads();
    #pragma unroll
    for (int i = 0; i < 32; i += 8)
        out[(size_t)(n0 + ty + i) * K + k0 + tx] = (__bf16)tile[tx][ty + i];
}

__global__ __launch_bounds__(256)
void prep_kernel(const float* __restrict__ x, __bf16* __restrict__ xb,
                 const float* __restrict__ W_omega, __bf16* __restrict__ womT,
                 const float* __restrict__ W1, __bf16* __restrict__ w1T,
                 const float* __restrict__ W2, __bf16* __restrict__ w2T)
{
    __shared__ float tile[32][33];
    const int bid = blockIdx.x;
    if (bid < 8192) {
        int i = bid * 256 + threadIdx.x;          // 2097152 float4's
        float4 v = ((const float4*)x)[i];
        bf16x4 o = { (__bf16)v.x, (__bf16)v.y, (__bf16)v.z, (__bf16)v.w };
        ((bf16x4*)xb)[i] = o;
    } else if (bid < 8448) {
        int t = bid - 8192;                       // 16 x 16
        transpose_tile(W_omega, womT, 512, 512, t & 15, t >> 4, tile);
    } else if (bid < 10496) {
        int t = bid - 8448;                       // 32 x 64
        transpose_tile(W1, w1T, 2048, 1024, t & 31, t >> 5, tile);
    } else {
        int t = bid - 10496;                      // 16 x 32
        transpose_tile(W2, w2T, 1024, 512, t & 15, t >> 4, tile);
    }
}

// ---------------------------------------------------------------------------
// bf16 MFMA GEMM (R7 structure): 128x128 tile, 4 waves, BK=64 double-buffered.
// Used for GEMM1 (MODE 0) and GEMM3 (MODE 2) where N=512 keeps 256^2 grids
// too small.
// ---------------------------------------------------------------------------
template<int MODE>
__global__ __launch_bounds__(256)
void gemm_kernel(const __bf16* __restrict__ A, const __bf16* __restrict__ Bt,
                 const float* __restrict__ bias, const __bf16* __restrict__ resid,
                 void* __restrict__ out, int M, int N, int K)
{
    __shared__ __bf16 As[2][128 * 64];
    __shared__ __bf16 Bs[2][128 * 64];

    const int tid     = threadIdx.x;
    const int tiles_n = N >> 7;                 // 4 or 8 (power of 2)
    const int ln_tn   = __ffs(tiles_n) - 1;
    const int per_m   = (M >> 7) >> 3;          // 128-row tiles per XCD

    const int xcd = blockIdx.x & 7;
    const int j   = blockIdx.x >> 3;
    const int tile_m = (xcd * per_m + (j >> ln_tn)) << 7;
    const int tile_n = (j & (tiles_n - 1)) << 7;

    const int wave = tid >> 6;
    const int lane = tid & 63;

    // staging map: lane l -> row (l>>3), chunk (l&7)^((l>>3)&7)
    const int srow = lane >> 3;                       // 0..7
    const int scol = ((lane & 7) ^ srow) << 3;        // elem offset in row

    const __bf16* Ags = A  + (size_t)(tile_m + wave * 32 + srow) * K + scol;
    const __bf16* Bgs = Bt + (size_t)(tile_n + wave * 32 + srow) * K + scol;

    const int m0 = (wave >> 1) << 6;
    const int n0 = (wave & 1) << 6;
    const int lr = lane & 15;
    const int q  = lane >> 4;
    const int l7 = lane & 7;
    const int fc0 = ((0 + q) ^ l7) << 3;   // swizzled elem offset, k-half 0
    const int fc1 = ((4 + q) ^ l7) << 3;   // swizzled elem offset, k-half 1

    f32x4 acc[4][4];
    #pragma unroll
    for (int i = 0; i < 4; ++i)
        #pragma unroll
        for (int jj = 0; jj < 4; ++jj)
            acc[i][jj] = (f32x4){0.f, 0.f, 0.f, 0.f};

    const int nIter = K >> 6;

    // prologue: stage tile 0 into buffer 0
    #pragma unroll
    for (int c = 0; c < 4; ++c) {
        load_lds16(Ags + (size_t)(c * 8) * K, &As[0][(wave * 32 + c * 8) * 64]);
        load_lds16(Bgs + (size_t)(c * 8) * K, &Bs[0][(wave * 32 + c * 8) * 64]);
    }

    for (int it = 0; it < nIter; ++it) {
        const int cur = it & 1;
        __syncthreads();   // drains prefetch issued last iter (aged thru MFMA)
        if (it + 1 < nIter) {
            const int nk = (it + 1) << 6;
            #pragma unroll
            for (int c = 0; c < 4; ++c) {
                load_lds16(Ags + nk + (size_t)(c * 8) * K, &As[cur ^ 1][(wave * 32 + c * 8) * 64]);
                load_lds16(Bgs + nk + (size_t)(c * 8) * K, &Bs[cur ^ 1][(wave * 32 + c * 8) * 64]);
            }
        }

        const __bf16* as = As[cur];
        const __bf16* bs = Bs[cur];
        // k-half 0
        {
            bf16x8 af[4], bq[4];
            #pragma unroll
            for (int i = 0; i < 4; ++i)
                af[i] = *(const bf16x8*)&as[(m0 + i * 16 + lr) * 64 + fc0];
            #pragma unroll
            for (int jj = 0; jj < 4; ++jj)
                bq[jj] = *(const bf16x8*)&bs[(n0 + jj * 16 + lr) * 64 + fc0];
            #pragma unroll
            for (int i = 0; i < 4; ++i)
                #pragma unroll
                for (int jj = 0; jj < 4; ++jj)
                    acc[i][jj] = __builtin_amdgcn_mfma_f32_16x16x32_bf16(af[i], bq[jj], acc[i][jj], 0, 0, 0);
        }
        // k-half 1
        {
            bf16x8 af[4], bq[4];
            #pragma unroll
            for (int i = 0; i < 4; ++i)
                af[i] = *(const bf16x8*)&as[(m0 + i * 16 + lr) * 64 + fc1];
            #pragma unroll
            for (int jj = 0; jj < 4; ++jj)
                bq[jj] = *(const bf16x8*)&bs[(n0 + jj * 16 + lr) * 64 + fc1];
            #pragma unroll
            for (int i = 0; i < 4; ++i)
                #pragma unroll
                for (int jj = 0; jj < 4; ++jj)
                    acc[i][jj] = __builtin_amdgcn_mfma_f32_16x16x32_bf16(af[i], bq[jj], acc[i][jj], 0, 0, 0);
        }
    }

    // epilogue — C/D layout: col = lane&15, row = (lane>>4)*4 + reg  [m89/m91]
    const int orow0 = tile_m + m0 + (q << 2);
    const int ocol0 = tile_n + n0 + lr;
    #pragma unroll
    for (int i = 0; i < 4; ++i) {
        #pragma unroll
        for (int jj = 0; jj < 4; ++jj) {
            const int col = ocol0 + jj * 16;
            const float bv = bias[col];
            #pragma unroll
            for (int r = 0; r < 4; ++r) {
                const int row = orow0 + i * 16 + r;
                float v = acc[i][jj][r] + bv;
                size_t idx = (size_t)row * N + col;
                if (MODE == 0) {
                    ((__bf16*)out)[idx] = (__bf16)v;
                } else if (MODE == 1) {
                    float g = 0.5f * v * (1.0f + erff(v * 0.70710678118654752f));
                    ((__bf16*)out)[idx] = (__bf16)g;
                } else {
                    ((float*)out)[idx] = v + (float)resid[idx];
                }
            }
        }
    }
}

// ---------------------------------------------------------------------------
// R11: 256x256-tile GEMM, 512 threads (8 waves, 2Mx4N), k-slice ring with a
// 2-deep register fragment pipeline.
//
// LDS = 4 slots x (A[256][32] + B[256][32]) bf16 = 128 KiB; slot s holds
// k-slice ks with ks%4==s. Phase ks (steady state):
//   vmcnt(8)            -- my stage(ks+1) retired; ks+2,ks+3 stay in flight
//   s_barrier           -- publishes stage(ks+1); certifies ALL waves drained
//                          their ds_reads of slot ks%4 (trailing lgkmcnt(0)
//                          of phase ks-1 ran before each wave arrived)
//   stage(ks+4)         -- overwrites slot ks%4 (safe per above)
//   ds_read slice ks+1  -- into the NEXT frag set (consumed next phase)
//   MFMA slice ks       -- current frag set, regs only, zero-wait
//   lgkmcnt(0)          -- drain my new reads before the next barrier
// Critical path per phase = the MFMA cluster; ds_read latency hides under
// it; HBM/L2 latency hides under 3-4 phases of counted-vmcnt pipeline.
//
// Rows are 64 B = 4 x 16B slots; slot XOR-swizzle s ^= (row>>1)&3 applied
// on BOTH the pre-swizzled global source (LDS dest linear) and the
// fragment ds_read (guideline 21). Requires NKS even and >= 4 (K=2048 here).
// Accumulation k-order identical to the 128^2 kernel.
// ---------------------------------------------------------------------------
template<int MODE>
__global__ __launch_bounds__(512, 1)
void gemm256_kernel(const __bf16* __restrict__ A, const __bf16* __restrict__ Bt,
                    const float* __restrict__ bias, void* __restrict__ out,
                    int M, int N, int K)
{
    __shared__ __bf16 As[4][256 * 32];
    __shared__ __bf16 Bs[4][256 * 32];

    const int tid  = threadIdx.x;
    const int wv   = tid >> 6;            // 0..7
    const int lane = tid & 63;
    const int wm   = wv >> 2;             // 0..1  (M half)
    const int wn   = wv & 3;              // 0..3  (N quarter)

    const int tiles_n = N >> 8;                    // 4 (power of 2)
    const int ln_tn   = __ffs(tiles_n) - 1;
    const int per_m   = (M >> 8) >> 3;             // 256-row tiles per XCD

    const int xcd = blockIdx.x & 7;
    const int j   = blockIdx.x >> 3;
    const int tile_m = (xcd * per_m + (j >> ln_tn)) << 8;
    const int tile_n = (j & (tiles_n - 1)) << 8;

    // --- staging constants ---------------------------------------------
    // issue q in {0,1} per operand: LDS row r = q*128 + 16*wv + (lane>>2),
    // LDS slot s = lane&3; global k-slot sigma = s ^ ((r>>1)&3)
    const int srow = 16 * wv + (lane >> 2);                       // 0..127
    const int sig8 = (((lane & 3) ^ ((lane >> 3) & 3)) << 3);     // elem off

    const __bf16* Ag = A  + (size_t)(tile_m + srow) * K + sig8;
    const __bf16* Bg = Bt + (size_t)(tile_n + srow) * K + sig8;
    const size_t rowK128 = (size_t)128 * K;
    const int lbase = wv * 512;            // wave-uniform LDS elem base

    // --- fragment-read constants ---------------------------------------
    const int lr    = lane & 15;           // row within 16-row fragment
    const int q4    = lane >> 4;           // logical 16B k-slot 0..3
    const int fslot = ((q4 ^ ((lane >> 1) & 3)) << 3);   // swizzled elem off
    const int arow0 = wm * 128 + lr;
    const int brow0 = wn * 64 + lr;

    f32x4 acc[8][4];
    #pragma unroll
    for (int i = 0; i < 8; ++i)
        #pragma unroll
        for (int jj = 0; jj < 4; ++jj)
            acc[i][jj] = (f32x4){0.f, 0.f, 0.f, 0.f};

    const int NKS = K >> 5;                // k-slices of 32 (even, >= 4)

    auto stage = [&](int ks) {
        const int slot = ks & 3;
        const __bf16* ag = Ag + (ks << 5);
        const __bf16* bg = Bg + (ks << 5);
        load_lds16(ag,           &As[slot][lbase]);
        load_lds16(ag + rowK128, &As[slot][4096 + lbase]);
        load_lds16(bg,           &Bs[slot][lbase]);
        load_lds16(bg + rowK128, &Bs[slot][4096 + lbase]);
    };

    bf16x8 afA[8], bqA[4], afB[8], bqB[4];

#define G256_READ(KS, NAF, NBQ)                                               \
    {                                                                         \
        const __bf16* as_ = As[(KS) & 3];                                     \
        const __bf16* bs_ = Bs[(KS) & 3];                                     \
        _Pragma("unroll")                                                     \
        for (int i_ = 0; i_ < 8; ++i_)                                        \
            NAF[i_] = *(const bf16x8*)&as_[(arow0 + i_ * 16) * 32 + fslot];   \
        _Pragma("unroll")                                                     \
        for (int j_ = 0; j_ < 4; ++j_)                                        \
            NBQ[j_] = *(const bf16x8*)&bs_[(brow0 + j_ * 16) * 32 + fslot];   \
    }

#define G256_PHASE(KS, CAF, CBQ, NAF, NBQ)                                    \
    {                                                                         \
        const int ks_ = (KS);                                                 \
        const int r_  = NKS - 1 - ks_;                                        \
        if (r_ >= 3)      asm volatile("s_waitcnt vmcnt(8)" ::: "memory");    \
        else if (r_ == 2) asm volatile("s_waitcnt vmcnt(4)" ::: "memory");    \
        else if (r_ == 1) asm volatile("s_waitcnt vmcnt(0)" ::: "memory");    \
        __builtin_amdgcn_s_barrier();                                         \
        asm volatile("" ::: "memory");                                        \
        if (ks_ + 4 < NKS) stage(ks_ + 4);                                    \
        if (ks_ + 1 < NKS) G256_READ(ks_ + 1, NAF, NBQ)                       \
        __builtin_amdgcn_s_setprio(1);                                        \
        _Pragma("unroll")                                                     \
        for (int i_ = 0; i_ < 8; ++i_)                                        \
            _Pragma("unroll")                                                 \
            for (int j_ = 0; j_ < 4; ++j_)                                    \
                acc[i_][j_] = __builtin_amdgcn_mfma_f32_16x16x32_bf16(        \
                    CAF[i_], CBQ[j_], acc[i_][j_], 0, 0, 0);                  \
        __builtin_amdgcn_s_setprio(0);                                        \
        asm volatile("s_waitcnt lgkmcnt(0)" ::: "memory");                    \
    }

    // prologue: slices 0..2 in flight, then certify slice 0 and preload its
    // fragments into set A (the ks=0 phase's "current" set).
    stage(0); stage(1); stage(2);
    asm volatile("s_waitcnt vmcnt(8)" ::: "memory");   // stage(0) retired
    __builtin_amdgcn_s_barrier();                      // slice 0 published
    asm volatile("" ::: "memory");
    stage(3);                                          // slot 3 (no conflict)
    G256_READ(0, afA, bqA)
    asm volatile("s_waitcnt lgkmcnt(0)" ::: "memory"); // drained before ks=0 barrier

    for (int ks = 0; ks < NKS; ks += 2) {
        G256_PHASE(ks,     afA, bqA, afB, bqB)
        G256_PHASE(ks + 1, afB, bqB, afA, bqA)
    }

#undef G256_PHASE
#undef G256_READ

    // epilogue — C/D layout: col = lane&15, row = (lane>>4)*4 + reg
    const int orow0 = tile_m + wm * 128 + (q4 << 2);
    const int ocol0 = tile_n + wn * 64 + lr;
    #pragma unroll
    for (int i = 0; i < 8; ++i) {
        #pragma unroll
        for (int jj = 0; jj < 4; ++jj) {
            const int col = ocol0 + jj * 16;
            const float bv = bias[col];
            #pragma unroll
            for (int r = 0; r < 4; ++r) {
                const int row = orow0 + i * 16 + r;
                float v = acc[i][jj][r] + bv;
                if (MODE == 1) {
                    float g = 0.5f * v * (1.0f + erff(v * 0.70710678118654752f));
                    ((__bf16*)out)[(size_t)row * N + col] = (__bf16)g;
                } else {
                    ((__bf16*)out)[(size_t)row * N + col] = (__bf16)v;
                }
            }
        }
    }
}

// ---------------------------------------------------------------------------
// Per-chunk phase cumsum + rotation + running means + LayerNorm.
// ---------------------------------------------------------------------------
__global__ __launch_bounds__(512)
void scan_ln_kernel(const __bf16* __restrict__ xb, const __bf16* __restrict__ omega,
                    const float* __restrict__ log_scale,
                    const float* __restrict__ gamma, const float* __restrict__ beta,
                    __bf16* __restrict__ ctx)
{
    const int chunk = blockIdx.x;        // 0..255  (b*64 + n)
    const int d     = threadIdx.x;       // 0..511
    const int lane  = d & 63, wv = d >> 6;   // 8 waves
    const size_t base = (size_t)chunk * 64 * 512;

    const float scale = expf(log_scale[d]);
    const float g0 = gamma[d], g1 = gamma[512 + d], g2 = gamma[1024 + d], g3 = gamma[1536 + d];
    const float e0 = beta[d],  e1 = beta[512 + d],  e2 = beta[1024 + d],  e3 = beta[1536 + d];

    float phi = 0.f, scr = 0.f, sci = 0.f;
    __shared__ float red[2][16];         // [slot][8 sums | 8 sumsq]

    float om_n = (float)omega[base + d];
    float xv_n = (float)xb[base + d];

    for (int c = 0; c < 64; ++c) {
        const float om = om_n;
        const float xv = xv_n;
        if (c < 63) {
            om_n = (float)omega[base + (size_t)(c + 1) * 512 + d];
            xv_n = (float)xb[base + (size_t)(c + 1) * 512 + d];
        }
        phi += om * scale * rsqrtf((float)(c + 1));
        float sp, cp;
        __sincosf(phi, &sp, &cp);
        const float cr = xv * cp, ci = xv * sp;
        scr += cr; sci += ci;
        const float inv = 1.0f / (float)(c + 1);
        const float mr = scr * inv, mi = sci * inv;
        const float rr = mr * cp + mi * sp;
        const float ri = mi * cp - mr * sp;

        float s  = cr + ci + rr + ri;
        float s2 = cr * cr + ci * ci + rr * rr + ri * ri;
        #pragma unroll
        for (int o = 32; o > 0; o >>= 1) {
            s  += __shfl_down(s, o);
            s2 += __shfl_down(s2, o);
        }
        if (lane == 0) { red[c & 1][wv] = s; red[c & 1][8 + wv] = s2; }
        __syncthreads();
        float S = 0.f, S2 = 0.f;
        #pragma unroll
        for (int i = 0; i < 8; ++i) { S += red[c & 1][i]; S2 += red[c & 1][8 + i]; }
        const float mu   = S * (1.0f / 2048.0f);
        const float var  = S2 * (1.0f / 2048.0f) - mu * mu;
        const float rstd = rsqrtf(var + 1e-5f);

        const size_t ob = ((size_t)chunk * 64 + c) * 2048;
        ctx[ob + d]        = (__bf16)(((cr - mu) * rstd) * g0 + e0);
        ctx[ob + 512 + d]  = (__bf16)(((ci - mu) * rstd) * g1 + e1);
        ctx[ob + 1024 + d] = (__bf16)(((rr - mu) * rstd) * g2 + e2);
        ctx[ob + 1536 + d] = (__bf16)(((ri - mu) * rstd) * g3 + e3);
    }
}

// ---------------------------------------------------------------------------
// Workspace layout (bytes):
//   xb    @ 0          : 16,777,216  (16384x512 bf16)
//   womT  @ 16777216   : 524,288     (512x512 bf16, transposed)
//   w1T   @ 17301504   : 4,194,304   (1024x2048 bf16, transposed)
//   w2T   @ 21495808   : 1,048,576   (512x1024 bf16, transposed)
//   omega @ 22544384   : 16,777,216  (16384x512 bf16) — region reused as h
//   h     @ 22544384   : 33,554,432  (16384x1024 bf16)
//   ctx   @ 56098816   : 67,108,864  (16384x2048 bf16)
// ---------------------------------------------------------------------------
extern "C" void kernel_launch(void* const* d_in, const int* in_sizes, int n_in,
                              void* d_out, int out_size, void* d_ws, size_t ws_size,
                              hipStream_t stream)
{
    const float* x         = (const float*)d_in[0];
    const float* W_omega   = (const float*)d_in[1];
    const float* b_omega   = (const float*)d_in[2];
    const float* log_scale = (const float*)d_in[3];
    const float* ln_gamma  = (const float*)d_in[4];
    const float* ln_beta   = (const float*)d_in[5];
    const float* W1        = (const float*)d_in[6];
    const float* b1        = (const float*)d_in[7];
    const float* W2        = (const float*)d_in[8];
    const float* b2        = (const float*)d_in[9];
    float* out = (float*)d_out;

    char* ws = (char*)d_ws;
    __bf16* xb    = (__bf16*)(ws);
    __bf16* womT  = (__bf16*)(ws + 16777216);
    __bf16* w1T   = (__bf16*)(ws + 17301504);
    __bf16* w2T   = (__bf16*)(ws + 21495808);
    __bf16* omega = (__bf16*)(ws + 22544384);
    __bf16* hbuf  = (__bf16*)(ws + 22544384);   // reuses omega region
    __bf16* ctx   = (__bf16*)(ws + 56098816);

    // 1. fused cast + weight transposes (one launch)
    prep_kernel<<<11008, 256, 0, stream>>>(x, xb, W_omega, womT, W1, w1T, W2, w2T);

    // 2. omega = x @ W_omega + b_omega   (bf16 out)
    gemm_kernel<0><<<512, 256, 0, stream>>>(xb, womT, b_omega, nullptr, omega, 16384, 512, 512);

    // 3. chunk scan + LayerNorm -> ctx (bf16, 16384x2048)
    scan_ln_kernel<<<256, 512, 0, stream>>>(xb, omega, log_scale, ln_gamma, ln_beta, ctx);

    // 4. h = gelu(ctx @ W1 + b1)  (bf16 out) — R11 ring + reg-pipeline kernel
    gemm256_kernel<1><<<256, 512, 0, stream>>>(ctx, w1T, b1, hbuf, 16384, 1024, 2048);

    // 5. out = x + h @ W2 + b2    (fp32 out, bf16 residual)
    gemm_kernel<2><<<512, 256, 0, stream>>>(hbuf, w2T, b2, xb, out, 16384, 512, 1024);
}

// Round 3
// 265.935 us; speedup vs baseline: 1.0742x; 1.0742x over previous
//
#include <hip/hip_runtime.h>
#include <hip/hip_bf16.h>
#include <math.h>

// ---------------------------------------------------------------------------
// PSI_47931835024047: x@W_omega -> chunked phase cumsum/rotation -> LN ->
//                     W1+gelu -> W2 + residual.
// B=4 S=4096 D=512 C=64. All GEMMs bf16 MFMA.
// R12: H1 = the compiler must assume plain-C++ LDS reads alias the in-flight
//      global_load_lds writes (runtime slot index) and inserts its own
//      vmcnt(0)-equivalent drain before EVERY phase's reads -- collapsing the
//      counted-vmcnt ring to depth 0 (explains R10==R11 at MfmaUtil ~25%).
//      Fix: fragment reads become inline-asm ds_read_b128 (opaque to alias
//      analysis, no memory clobber), raw 32-bit LDS offsets + imm offset:.
//      Phase-end lgkmcnt(0) + sched_barrier(0) (rule #18) is the read->MFMA
//      fence. Ring/swizzle/numerics identical to R11.
// ---------------------------------------------------------------------------

typedef __bf16 bf16x8 __attribute__((ext_vector_type(8)));
typedef __bf16 bf16x4 __attribute__((ext_vector_type(4)));
typedef __bf16 bf16x2 __attribute__((ext_vector_type(2)));
typedef float  f32x4  __attribute__((ext_vector_type(4)));

typedef __attribute__((address_space(1))) void* gas_ptr;
typedef __attribute__((address_space(3))) void* las_ptr;

// wave-uniform LDS base; each lane deposits 16 B at base + lane*16
__device__ __forceinline__ void load_lds16(const void* g, void* l) {
    __builtin_amdgcn_global_load_lds((gas_ptr)g, (las_ptr)l, 16, 0, 0);
}

// ---------------------------------------------------------------------------
// Fused prep: block ranges do (a) x->bf16 cast, (b) W_omega^T, (c) W1^T,
// (d) W2^T. One launch instead of four.
// ---------------------------------------------------------------------------
__device__ __forceinline__ void transpose_tile(const float* __restrict__ in,
                                               __bf16* __restrict__ out,
                                               int K, int N, int bx, int by,
                                               float (*tile)[33])
{
    const int tid = threadIdx.x;
    const int tx = tid & 31, ty = tid >> 5;       // (32, 8)
    const int n0 = bx * 32, k0 = by * 32;
    #pragma unroll
    for (int i = 0; i < 32; i += 8)
        tile[ty + i][tx] = in[(size_t)(k0 + ty + i) * N + n0 + tx];
    __syncthreads();
    #pragma unroll
    for (int i = 0; i < 32; i += 8)
        out[(size_t)(n0 + ty + i) * K + k0 + tx] = (__bf16)tile[tx][ty + i];
}

__global__ __launch_bounds__(256)
void prep_kernel(const float* __restrict__ x, __bf16* __restrict__ xb,
                 const float* __restrict__ W_omega, __bf16* __restrict__ womT,
                 const float* __restrict__ W1, __bf16* __restrict__ w1T,
                 const float* __restrict__ W2, __bf16* __restrict__ w2T)
{
    __shared__ float tile[32][33];
    const int bid = blockIdx.x;
    if (bid < 8192) {
        int i = bid * 256 + threadIdx.x;          // 2097152 float4's
        float4 v = ((const float4*)x)[i];
        bf16x4 o = { (__bf16)v.x, (__bf16)v.y, (__bf16)v.z, (__bf16)v.w };
        ((bf16x4*)xb)[i] = o;
    } else if (bid < 8448) {
        int t = bid - 8192;                       // 16 x 16
        transpose_tile(W_omega, womT, 512, 512, t & 15, t >> 4, tile);
    } else if (bid < 10496) {
        int t = bid - 8448;                       // 32 x 64
        transpose_tile(W1, w1T, 2048, 1024, t & 31, t >> 5, tile);
    } else {
        int t = bid - 10496;                      // 16 x 32
        transpose_tile(W2, w2T, 1024, 512, t & 15, t >> 4, tile);
    }
}

// ---------------------------------------------------------------------------
// bf16 MFMA GEMM (R7 structure): 128x128 tile, 4 waves, BK=64 double-buffered.
// Used for GEMM1 (MODE 0) and GEMM3 (MODE 2) where N=512 keeps 256^2 grids
// too small.
// ---------------------------------------------------------------------------
template<int MODE>
__global__ __launch_bounds__(256)
void gemm_kernel(const __bf16* __restrict__ A, const __bf16* __restrict__ Bt,
                 const float* __restrict__ bias, const __bf16* __restrict__ resid,
                 void* __restrict__ out, int M, int N, int K)
{
    __shared__ __bf16 As[2][128 * 64];
    __shared__ __bf16 Bs[2][128 * 64];

    const int tid     = threadIdx.x;
    const int tiles_n = N >> 7;                 // 4 or 8 (power of 2)
    const int ln_tn   = __ffs(tiles_n) - 1;
    const int per_m   = (M >> 7) >> 3;          // 128-row tiles per XCD

    const int xcd = blockIdx.x & 7;
    const int j   = blockIdx.x >> 3;
    const int tile_m = (xcd * per_m + (j >> ln_tn)) << 7;
    const int tile_n = (j & (tiles_n - 1)) << 7;

    const int wave = tid >> 6;
    const int lane = tid & 63;

    // staging map: lane l -> row (l>>3), chunk (l&7)^((l>>3)&7)
    const int srow = lane >> 3;                       // 0..7
    const int scol = ((lane & 7) ^ srow) << 3;        // elem offset in row

    const __bf16* Ags = A  + (size_t)(tile_m + wave * 32 + srow) * K + scol;
    const __bf16* Bgs = Bt + (size_t)(tile_n + wave * 32 + srow) * K + scol;

    const int m0 = (wave >> 1) << 6;
    const int n0 = (wave & 1) << 6;
    const int lr = lane & 15;
    const int q  = lane >> 4;
    const int l7 = lane & 7;
    const int fc0 = ((0 + q) ^ l7) << 3;   // swizzled elem offset, k-half 0
    const int fc1 = ((4 + q) ^ l7) << 3;   // swizzled elem offset, k-half 1

    f32x4 acc[4][4];
    #pragma unroll
    for (int i = 0; i < 4; ++i)
        #pragma unroll
        for (int jj = 0; jj < 4; ++jj)
            acc[i][jj] = (f32x4){0.f, 0.f, 0.f, 0.f};

    const int nIter = K >> 6;

    // prologue: stage tile 0 into buffer 0
    #pragma unroll
    for (int c = 0; c < 4; ++c) {
        load_lds16(Ags + (size_t)(c * 8) * K, &As[0][(wave * 32 + c * 8) * 64]);
        load_lds16(Bgs + (size_t)(c * 8) * K, &Bs[0][(wave * 32 + c * 8) * 64]);
    }

    for (int it = 0; it < nIter; ++it) {
        const int cur = it & 1;
        __syncthreads();   // drains prefetch issued last iter (aged thru MFMA)
        if (it + 1 < nIter) {
            const int nk = (it + 1) << 6;
            #pragma unroll
            for (int c = 0; c < 4; ++c) {
                load_lds16(Ags + nk + (size_t)(c * 8) * K, &As[cur ^ 1][(wave * 32 + c * 8) * 64]);
                load_lds16(Bgs + nk + (size_t)(c * 8) * K, &Bs[cur ^ 1][(wave * 32 + c * 8) * 64]);
            }
        }

        const __bf16* as = As[cur];
        const __bf16* bs = Bs[cur];
        // k-half 0
        {
            bf16x8 af[4], bq[4];
            #pragma unroll
            for (int i = 0; i < 4; ++i)
                af[i] = *(const bf16x8*)&as[(m0 + i * 16 + lr) * 64 + fc0];
            #pragma unroll
            for (int jj = 0; jj < 4; ++jj)
                bq[jj] = *(const bf16x8*)&bs[(n0 + jj * 16 + lr) * 64 + fc0];
            #pragma unroll
            for (int i = 0; i < 4; ++i)
                #pragma unroll
                for (int jj = 0; jj < 4; ++jj)
                    acc[i][jj] = __builtin_amdgcn_mfma_f32_16x16x32_bf16(af[i], bq[jj], acc[i][jj], 0, 0, 0);
        }
        // k-half 1
        {
            bf16x8 af[4], bq[4];
            #pragma unroll
            for (int i = 0; i < 4; ++i)
                af[i] = *(const bf16x8*)&as[(m0 + i * 16 + lr) * 64 + fc1];
            #pragma unroll
            for (int jj = 0; jj < 4; ++jj)
                bq[jj] = *(const bf16x8*)&bs[(n0 + jj * 16 + lr) * 64 + fc1];
            #pragma unroll
            for (int i = 0; i < 4; ++i)
                #pragma unroll
                for (int jj = 0; jj < 4; ++jj)
                    acc[i][jj] = __builtin_amdgcn_mfma_f32_16x16x32_bf16(af[i], bq[jj], acc[i][jj], 0, 0, 0);
        }
    }

    // epilogue — C/D layout: col = lane&15, row = (lane>>4)*4 + reg  [m89/m91]
    const int orow0 = tile_m + m0 + (q << 2);
    const int ocol0 = tile_n + n0 + lr;
    #pragma unroll
    for (int i = 0; i < 4; ++i) {
        #pragma unroll
        for (int jj = 0; jj < 4; ++jj) {
            const int col = ocol0 + jj * 16;
            const float bv = bias[col];
            #pragma unroll
            for (int r = 0; r < 4; ++r) {
                const int row = orow0 + i * 16 + r;
                float v = acc[i][jj][r] + bv;
                size_t idx = (size_t)row * N + col;
                if (MODE == 0) {
                    ((__bf16*)out)[idx] = (__bf16)v;
                } else if (MODE == 1) {
                    float g = 0.5f * v * (1.0f + erff(v * 0.70710678118654752f));
                    ((__bf16*)out)[idx] = (__bf16)g;
                } else {
                    ((float*)out)[idx] = v + (float)resid[idx];
                }
            }
        }
    }
}

// ---------------------------------------------------------------------------
// R12: 256x256-tile GEMM, 512 threads (8 waves, 2Mx4N), 4-slot k-slice ring,
// 2-deep register fragment pipeline, ASM ds_read fragment loads.
//
// Phase ks (steady state):
//   vmcnt(8)            -- my stage(ks+1) retired; ks+2,ks+3 stay in flight
//   s_barrier           -- publishes stage(ks+1) across waves
//   stage(ks+4)         -- overwrites slot ks%4 (drained: reads of slice ks
//                          happened phase ks-1, fenced by its lgkmcnt(0))
//   asm ds_read slice ks+1 -> next frag set (12 x ds_read_b128, opaque to
//                          alias analysis => NO compiler vmcnt drain)
//   MFMA slice ks       -- current frag set, regs only
//   lgkmcnt(0) + sched_barrier(0)  -- fence reads before next barrier
//
// LDS slot stride 16384 B; fragment addrs = base + slot*16384 + i*1024 with
// the slot add as one VALU and i*1024 as the ds_read imm offset.
// Swizzle (both-sides, verified R10/R11): staging sigma = (lane&3)^((lane>>3)&3),
// read fslot = (q4 ^ ((lane>>1)&3)). Requires NKS even, >= 4 (K=2048: NKS=64).
// ---------------------------------------------------------------------------
template<int MODE>
__global__ __launch_bounds__(512, 1)
void gemm256_kernel(const __bf16* __restrict__ A, const __bf16* __restrict__ Bt,
                    const float* __restrict__ bias, void* __restrict__ out,
                    int M, int N, int K)
{
    __shared__ __bf16 As[4][256 * 32];
    __shared__ __bf16 Bs[4][256 * 32];

    const int tid  = threadIdx.x;
    const int wv   = tid >> 6;            // 0..7
    const int lane = tid & 63;
    const int wm   = wv >> 2;             // 0..1  (M half)
    const int wn   = wv & 3;              // 0..3  (N quarter)

    const int tiles_n = N >> 8;                    // 4 (power of 2)
    const int ln_tn   = __ffs(tiles_n) - 1;
    const int per_m   = (M >> 8) >> 3;             // 256-row tiles per XCD

    const int xcd = blockIdx.x & 7;
    const int j   = blockIdx.x >> 3;
    const int tile_m = (xcd * per_m + (j >> ln_tn)) << 8;
    const int tile_n = (j & (tiles_n - 1)) << 8;

    // --- staging constants ---------------------------------------------
    const int srow = 16 * wv + (lane >> 2);                       // 0..127
    const int sig8 = (((lane & 3) ^ ((lane >> 3) & 3)) << 3);     // elem off

    const __bf16* Ag = A  + (size_t)(tile_m + srow) * K + sig8;
    const __bf16* Bg = Bt + (size_t)(tile_n + srow) * K + sig8;
    const size_t rowK128 = (size_t)128 * K;
    const int lbase = wv * 512;            // wave-uniform LDS elem base

    // --- fragment-read constants ---------------------------------------
    const int lr    = lane & 15;           // row within 16-row fragment
    const int q4    = lane >> 4;           // logical 16B k-slot 0..3
    const int fslot = ((q4 ^ ((lane >> 1) & 3)) << 3);   // swizzled elem off
    const int arow0 = wm * 128 + lr;
    const int brow0 = wn * 64 + lr;

    // raw 32-bit LDS byte addresses of slot-0 fragments
    const unsigned ldsA0 = (unsigned)(size_t)(las_ptr)&As[0][0];
    const unsigned ldsB0 = (unsigned)(size_t)(las_ptr)&Bs[0][0];
    const unsigned asA = ldsA0 + (unsigned)((arow0 * 32 + fslot) << 1);
    const unsigned asB = ldsB0 + (unsigned)((brow0 * 32 + fslot) << 1);

    f32x4 acc[8][4];
    #pragma unroll
    for (int i = 0; i < 8; ++i)
        #pragma unroll
        for (int jj = 0; jj < 4; ++jj)
            acc[i][jj] = (f32x4){0.f, 0.f, 0.f, 0.f};

    const int NKS = K >> 5;                // k-slices of 32 (even, >= 4)

    auto stage = [&](int ks) {
        const int slot = ks & 3;
        const __bf16* ag = Ag + (ks << 5);
        const __bf16* bg = Bg + (ks << 5);
        load_lds16(ag,           &As[slot][lbase]);
        load_lds16(ag + rowK128, &As[slot][4096 + lbase]);
        load_lds16(bg,           &Bs[slot][lbase]);
        load_lds16(bg + rowK128, &Bs[slot][4096 + lbase]);
    };

    bf16x8 afA[8], bqA[4], afB[8], bqB[4];

#define DSR(d, a, o) asm volatile("ds_read_b128 %0, %1 offset:" o \
                                  : "=v"(d) : "v"(a))

#define G256_READ(KS, NAF, NBQ)                                               \
    {                                                                         \
        const unsigned aA_ = asA + (unsigned)(((KS) & 3) << 14);              \
        const unsigned aB_ = asB + (unsigned)(((KS) & 3) << 14);              \
        DSR(NAF[0], aA_, "0");    DSR(NAF[1], aA_, "1024");                   \
        DSR(NAF[2], aA_, "2048"); DSR(NAF[3], aA_, "3072");                   \
        DSR(NAF[4], aA_, "4096"); DSR(NAF[5], aA_, "5120");                   \
        DSR(NAF[6], aA_, "6144"); DSR(NAF[7], aA_, "7168");                   \
        DSR(NBQ[0], aB_, "0");    DSR(NBQ[1], aB_, "1024");                   \
        DSR(NBQ[2], aB_, "2048"); DSR(NBQ[3], aB_, "3072");                   \
    }

#define G256_PHASE(KS, CAF, CBQ, NAF, NBQ)                                    \
    {                                                                         \
        const int ks_ = (KS);                                                 \
        const int r_  = NKS - 1 - ks_;                                        \
        if (r_ >= 3)      asm volatile("s_waitcnt vmcnt(8)" ::: "memory");    \
        else if (r_ == 2) asm volatile("s_waitcnt vmcnt(4)" ::: "memory");    \
        else if (r_ == 1) asm volatile("s_waitcnt vmcnt(0)" ::: "memory");    \
        __builtin_amdgcn_s_barrier();                                         \
        asm volatile("" ::: "memory");                                        \
        if (ks_ + 4 < NKS) stage(ks_ + 4);                                    \
        if (ks_ + 1 < NKS) G256_READ(ks_ + 1, NAF, NBQ)                       \
        __builtin_amdgcn_s_setprio(1);                                        \
        _Pragma("unroll")                                                     \
        for (int i_ = 0; i_ < 8; ++i_)                                        \
            _Pragma("unroll")                                                 \
            for (int j_ = 0; j_ < 4; ++j_)                                    \
                acc[i_][j_] = __builtin_amdgcn_mfma_f32_16x16x32_bf16(        \
                    CAF[i_], CBQ[j_], acc[i_][j_], 0, 0, 0);                  \
        __builtin_amdgcn_s_setprio(0);                                        \
        asm volatile("s_waitcnt lgkmcnt(0)" ::: "memory");                    \
        __builtin_amdgcn_sched_barrier(0);                                    \
    }

    // prologue: slices 0..2 in flight, then certify slice 0 and preload its
    // fragments into set A (the ks=0 phase's "current" set).
    stage(0); stage(1); stage(2);
    asm volatile("s_waitcnt vmcnt(8)" ::: "memory");   // stage(0) retired
    __builtin_amdgcn_s_barrier();                      // slice 0 published
    asm volatile("" ::: "memory");
    stage(3);                                          // slot 3 (no conflict)
    G256_READ(0, afA, bqA)
    asm volatile("s_waitcnt lgkmcnt(0)" ::: "memory"); // drained before ks=0 barrier
    __builtin_amdgcn_sched_barrier(0);

    for (int ks = 0; ks < NKS; ks += 2) {
        G256_PHASE(ks,     afA, bqA, afB, bqB)
        G256_PHASE(ks + 1, afB, bqB, afA, bqA)
    }

#undef G256_PHASE
#undef G256_READ
#undef DSR

    // epilogue — C/D layout: col = lane&15, row = (lane>>4)*4 + reg
    const int orow0 = tile_m + wm * 128 + (q4 << 2);
    const int ocol0 = tile_n + wn * 64 + lr;
    #pragma unroll
    for (int i = 0; i < 8; ++i) {
        #pragma unroll
        for (int jj = 0; jj < 4; ++jj) {
            const int col = ocol0 + jj * 16;
            const float bv = bias[col];
            #pragma unroll
            for (int r = 0; r < 4; ++r) {
                const int row = orow0 + i * 16 + r;
                float v = acc[i][jj][r] + bv;
                if (MODE == 1) {
                    float g = 0.5f * v * (1.0f + erff(v * 0.70710678118654752f));
                    ((__bf16*)out)[(size_t)row * N + col] = (__bf16)g;
                } else {
                    ((__bf16*)out)[(size_t)row * N + col] = (__bf16)v;
                }
            }
        }
    }
}

// ---------------------------------------------------------------------------
// Per-chunk phase cumsum + rotation + running means + LayerNorm.
// ---------------------------------------------------------------------------
__global__ __launch_bounds__(512)
void scan_ln_kernel(const __bf16* __restrict__ xb, const __bf16* __restrict__ omega,
                    const float* __restrict__ log_scale,
                    const float* __restrict__ gamma, const float* __restrict__ beta,
                    __bf16* __restrict__ ctx)
{
    const int chunk = blockIdx.x;        // 0..255  (b*64 + n)
    const int d     = threadIdx.x;       // 0..511
    const int lane  = d & 63, wv = d >> 6;   // 8 waves
    const size_t base = (size_t)chunk * 64 * 512;

    const float scale = expf(log_scale[d]);
    const float g0 = gamma[d], g1 = gamma[512 + d], g2 = gamma[1024 + d], g3 = gamma[1536 + d];
    const float e0 = beta[d],  e1 = beta[512 + d],  e2 = beta[1024 + d],  e3 = beta[1536 + d];

    float phi = 0.f, scr = 0.f, sci = 0.f;
    __shared__ float red[2][16];         // [slot][8 sums | 8 sumsq]

    float om_n = (float)omega[base + d];
    float xv_n = (float)xb[base + d];

    for (int c = 0; c < 64; ++c) {
        const float om = om_n;
        const float xv = xv_n;
        if (c < 63) {
            om_n = (float)omega[base + (size_t)(c + 1) * 512 + d];
            xv_n = (float)xb[base + (size_t)(c + 1) * 512 + d];
        }
        phi += om * scale * rsqrtf((float)(c + 1));
        float sp, cp;
        __sincosf(phi, &sp, &cp);
        const float cr = xv * cp, ci = xv * sp;
        scr += cr; sci += ci;
        const float inv = 1.0f / (float)(c + 1);
        const float mr = scr * inv, mi = sci * inv;
        const float rr = mr * cp + mi * sp;
        const float ri = mi * cp - mr * sp;

        float s  = cr + ci + rr + ri;
        float s2 = cr * cr + ci * ci + rr * rr + ri * ri;
        #pragma unroll
        for (int o = 32; o > 0; o >>= 1) {
            s  += __shfl_down(s, o);
            s2 += __shfl_down(s2, o);
        }
        if (lane == 0) { red[c & 1][wv] = s; red[c & 1][8 + wv] = s2; }
        __syncthreads();
        float S = 0.f, S2 = 0.f;
        #pragma unroll
        for (int i = 0; i < 8; ++i) { S += red[c & 1][i]; S2 += red[c & 1][8 + i]; }
        const float mu   = S * (1.0f / 2048.0f);
        const float var  = S2 * (1.0f / 2048.0f) - mu * mu;
        const float rstd = rsqrtf(var + 1e-5f);

        const size_t ob = ((size_t)chunk * 64 + c) * 2048;
        ctx[ob + d]        = (__bf16)(((cr - mu) * rstd) * g0 + e0);
        ctx[ob + 512 + d]  = (__bf16)(((ci - mu) * rstd) * g1 + e1);
        ctx[ob + 1024 + d] = (__bf16)(((rr - mu) * rstd) * g2 + e2);
        ctx[ob + 1536 + d] = (__bf16)(((ri - mu) * rstd) * g3 + e3);
    }
}

// ---------------------------------------------------------------------------
// Workspace layout (bytes):
//   xb    @ 0          : 16,777,216  (16384x512 bf16)
//   womT  @ 16777216   : 524,288     (512x512 bf16, transposed)
//   w1T   @ 17301504   : 4,194,304   (1024x2048 bf16, transposed)
//   w2T   @ 21495808   : 1,048,576   (512x1024 bf16, transposed)
//   omega @ 22544384   : 16,777,216  (16384x512 bf16) — region reused as h
//   h     @ 22544384   : 33,554,432  (16384x1024 bf16)
//   ctx   @ 56098816   : 67,108,864  (16384x2048 bf16)
// ---------------------------------------------------------------------------
extern "C" void kernel_launch(void* const* d_in, const int* in_sizes, int n_in,
                              void* d_out, int out_size, void* d_ws, size_t ws_size,
                              hipStream_t stream)
{
    const float* x         = (const float*)d_in[0];
    const float* W_omega   = (const float*)d_in[1];
    const float* b_omega   = (const float*)d_in[2];
    const float* log_scale = (const float*)d_in[3];
    const float* ln_gamma  = (const float*)d_in[4];
    const float* ln_beta   = (const float*)d_in[5];
    const float* W1        = (const float*)d_in[6];
    const float* b1        = (const float*)d_in[7];
    const float* W2        = (const float*)d_in[8];
    const float* b2        = (const float*)d_in[9];
    float* out = (float*)d_out;

    char* ws = (char*)d_ws;
    __bf16* xb    = (__bf16*)(ws);
    __bf16* womT  = (__bf16*)(ws + 16777216);
    __bf16* w1T   = (__bf16*)(ws + 17301504);
    __bf16* w2T   = (__bf16*)(ws + 21495808);
    __bf16* omega = (__bf16*)(ws + 22544384);
    __bf16* hbuf  = (__bf16*)(ws + 22544384);   // reuses omega region
    __bf16* ctx   = (__bf16*)(ws + 56098816);

    // 1. fused cast + weight transposes (one launch)
    prep_kernel<<<11008, 256, 0, stream>>>(x, xb, W_omega, womT, W1, w1T, W2, w2T);

    // 2. omega = x @ W_omega + b_omega   (bf16 out)
    gemm_kernel<0><<<512, 256, 0, stream>>>(xb, womT, b_omega, nullptr, omega, 16384, 512, 512);

    // 3. chunk scan + LayerNorm -> ctx (bf16, 16384x2048)
    scan_ln_kernel<<<256, 512, 0, stream>>>(xb, omega, log_scale, ln_gamma, ln_beta, ctx);

    // 4. h = gelu(ctx @ W1 + b1)  (bf16 out) — R12 ring + asm ds_read kernel
    gemm256_kernel<1><<<256, 512, 0, stream>>>(ctx, w1T, b1, hbuf, 16384, 1024, 2048);

    // 5. out = x + h @ W2 + b2    (fp32 out, bf16 residual)
    gemm_kernel<2><<<512, 256, 0, stream>>>(hbuf, w2T, b2, xb, out, 16384, 512, 1024);
}